// Round 9
// baseline (382.291 us; speedup 1.0000x reference)
//
#include <hip/hip_runtime.h>

// Involution2d fused, MFMA + sliding-window involution.
// Block = (batch, 8-row x 16-col tile), 256 threads / 4 waves, 2 blocks/CU.
// Phase 1: rT[p][o] = bf16(ReLU(BN(w_reduce @ x)))   via mfma 16x16x32 bf16
// Phase 2 per group: P0 {halo LDS writes + kernel-gen MFMA -> s_w} / bar /
//   P1 {prefetch g+1 + involution 4px x 2 planes per lane, all 4 waves} / bar.
// R2: lgkm-only barriers + register-staged prefetch (300->106us).
// R4 FAILED: wave-specialized staging -> spills. R5 NEG: LDS volume not binding.
// R7: s_a eliminated, 2 barriers/group (106->101). R8: XCD swizzle - batch
//   pinned to one XCD; FETCH 230->66.7MB (halo reads all L2-hit) but dur
//   only 101->92: traffic fixed, latency chain remains.
// R9: all pipes <40%, 2 waves/SIMD -> critical path = intra-wave LDS-read
//   latency in the serial (#pragma unroll 1) involution i-loop:
//   7 x {13 ds_read -> ~120cy wait -> 112cy fma}. Fix: depth-2 software
//   pipeline with two NAMED register sets (compile-time indices only):
//   iter i+1's reads issue before iter i's fma block -> read latency
//   hidden under fma issue. +~100 VGPR, fine (occupancy is LDS-capped).

typedef __attribute__((ext_vector_type(8))) short bf16x8;
typedef __attribute__((ext_vector_type(4))) float f32x4;

namespace {
constexpr int Cn = 256, Hn = 64, Wn = 64, HWn = 4096;
constexpr int Gn = 16, CGn = 16, CRn = 64;
constexpr int Kn = 7, PADn = 3, KKn = 49;
constexpr int TH = 8, TW = 16, TP = 128;   // tile pixels
constexpr int LD = 72, LDW = 36;           // bf16 row stride (64 + 8 pad) / dwords
constexpr int WLD = 132;                   // s_w fp32 row stride (128 px + 4 pad)
constexpr int XROW = 24, XPS = 336;        // halo row / plane stride (dwords); linear
}

__device__ __forceinline__ unsigned short bf16rne(float f) {
  unsigned u = __float_as_uint(f);
  u += 0x7fffu + ((u >> 16) & 1u);
  return (unsigned short)(u >> 16);
}
__device__ __forceinline__ unsigned packbf2(float a, float b) {
  return (unsigned)bf16rne(a) | ((unsigned)bf16rne(b) << 16);
}

// lgkm-only barrier: LDS producer/consumer ordering WITHOUT draining vmcnt,
// so register-staged global prefetch loads stay in flight across it.
__device__ __forceinline__ void bar_lgkm() {
  asm volatile("s_waitcnt lgkmcnt(0)" ::: "memory");
  __builtin_amdgcn_s_barrier();
}

__global__ __launch_bounds__(256, 2) void invol_fused(
    const float* __restrict__ x, const float* __restrict__ w_reduce,
    const float* __restrict__ w_span, const float* __restrict__ bn_gamma,
    const float* __restrict__ bn_beta, const float* __restrict__ bn_mean,
    const float* __restrict__ bn_var, float* __restrict__ out)
{
  __shared__ __align__(16) unsigned short s_rT[TP * LD];   // 18.4 KB, persists
  __shared__ __align__(16) float s_u[KKn * WLD];           // 25.9 KB: ph1 xT bf16 / ph2 s_w fp32
  __shared__ __align__(16) float s_xh[16 * XPS];           // 21.5 KB: 16 halo planes, linear

  const int t = threadIdx.x;
  const int lane = t & 63, q = t >> 6;
  const int m16 = lane & 15, quad = lane >> 4;
  const int s = lane >> 5;                 // half of wave -> cg split
  const int slot = lane & 31;
  const int py = slot >> 2, px0 = (slot & 3) * 4;

  // XCD-aware block swizzle: batch b -> XCD b&7; a batch's 32 tiles share
  // one XCD's L2 so group x-slabs are fetched once per XCD (R8: -71% FETCH).
  const int bid = blockIdx.x;              // 0..511
  const int xcd = bid & 7;
  const int jj  = bid >> 3;                // 0..63 within XCD
  const int b   = xcd + 8 * (jj >> 5);     // batches {xcd, xcd+8}
  const int tile = jj & 31;                // 0..31 -> 8x4 tile grid
  const int h0 = (tile >> 2) * TH;
  const int w0 = (tile & 3) * TW;
  const long xbase = (long)b * Cn * HWn;

  // BN constants for this lane's phase-1 D rows (o = q*16 + quad*4 + r)
  float bsc[4], bsh[4];
  {
    int ob = q * 16 + quad * 4;
#pragma unroll
    for (int r = 0; r < 4; ++r) {
      float sc = bn_gamma[ob + r] * rsqrtf(bn_var[ob + r] + 1e-5f);
      bsc[r] = sc;
      bsh[r] = bn_beta[ob + r] - bn_mean[ob + r] * sc;
    }
  }

  // ---------------- Phase 1: rT = bf16(ReLU(BN(w_reduce @ x))) ----------------
  f32x4 pac[8];
#pragma unroll
  for (int pt = 0; pt < 8; ++pt) pac[pt] = (f32x4){0.f, 0.f, 0.f, 0.f};

  unsigned short* xT = (unsigned short*)s_u;  // [128 p][72] bf16

  float pxa[16], pxb[16];
  f32x4 pA1[4];
  const float* wrrow = w_reduce + (q * 16 + m16) * Cn;   // this lane's A row

  auto issue_cc = [&](int cc) {
#pragma unroll
    for (int h = 0; h < 4; ++h)   // A frag: cols cc + ks*32 + quad*8 + h4
      pA1[h] = *(const f32x4*)(wrrow + cc + (h >> 1) * 32 + quad * 8 + (h & 1) * 4);
#pragma unroll
    for (int it = 0; it < 16; ++it) {
      int idx = t + it * 256;
      int pp = idx & 127, cp = idx >> 7;
      const float* gp = x + xbase + (long)(cc + cp * 2) * HWn
                        + (h0 + (pp >> 4)) * Wn + (w0 + (pp & 15));
      pxa[it] = gp[0];
      pxb[it] = gp[HWn];
    }
  };

  issue_cc(0);
  for (int cc = 0; cc < Cn; cc += 64) {
    bar_lgkm();
#pragma unroll
    for (int it = 0; it < 16; ++it) {       // xT[p][c] bf16 (2 ch packed)
      int idx = t + it * 256;
      int pp = idx & 127, cp = idx >> 7;
      ((unsigned*)xT)[pp * LDW + cp] = packbf2(pxa[it], pxb[it]);
    }
    bf16x8 afr[2];                          // pack A-frag before regs reused
#pragma unroll
    for (int ks = 0; ks < 2; ++ks) {
      unsigned* ap = (unsigned*)&afr[ks];
      f32x4 lo = pA1[ks * 2], hi = pA1[ks * 2 + 1];
      ap[0] = packbf2(lo[0], lo[1]); ap[1] = packbf2(lo[2], lo[3]);
      ap[2] = packbf2(hi[0], hi[1]); ap[3] = packbf2(hi[2], hi[3]);
    }
    if (cc + 64 < Cn) issue_cc(cc + 64);    // prefetch next cc-step
    bar_lgkm();
#pragma unroll
    for (int ks = 0; ks < 2; ++ks) {
#pragma unroll
      for (int pt = 0; pt < 8; ++pt) {
        bf16x8 bf = *(const bf16x8*)(xT + (pt * 16 + m16) * LD + ks * 32 + quad * 8);
        pac[pt] = __builtin_amdgcn_mfma_f32_16x16x32_bf16(afr[ks], bf, pac[pt], 0, 0, 0);
      }
    }
  }

  // g-invariant halo addressing, hoisted: plane-relative offset or -1.
  int hoff[21];
#pragma unroll
  for (int it = 0; it < 21; ++it) {
    int idx = t + it * 256;
    int pl = idx / 336, rem = idx - pl * 336;
    int iy = rem / XROW, ix = rem - iy * XROW;   // ix 22,23: harmless pad
    int gy = h0 + iy - PADn, gx = w0 + ix - PADn;
    hoff[it] = ((unsigned)gy < (unsigned)Hn && (unsigned)gx < (unsigned)Wn)
                   ? pl * HWn + gy * Wn + gx : -1;
  }

  // phase-2 staging regs (all 256 threads; proven spill-free scale)
  float ph[21];
  f32x4 pA2[4];
  const int wrow = q * 16 + m16;            // A row for kgen (rows>=49 discarded)
  const int wclamp = (wrow < KKn ? wrow : 0);
  auto issue_g = [&](int g) {
    const float* wsrow = w_span + ((long)g * KKn + wclamp) * CRn;
#pragma unroll
    for (int h = 0; h < 4; ++h)
      pA2[h] = *(const f32x4*)(wsrow + (h >> 1) * 32 + quad * 8 + (h & 1) * 4);
    const float* xg = x + xbase + (long)g * CGn * HWn;
#pragma unroll
    for (int it = 0; it < 21; ++it)
      ph[it] = (hoff[it] >= 0) ? xg[hoff[it]] : 0.f;
  };

  issue_g(0);  // loads fly over epilogue + pre-loop barrier

  // epilogue: BN+ReLU -> rT[p][o] bf16 pairs
#pragma unroll
  for (int pt = 0; pt < 8; ++pt) {
    int pp = pt * 16 + m16;
    float v0 = fmaxf(fmaf(pac[pt][0], bsc[0], bsh[0]), 0.f);
    float v1 = fmaxf(fmaf(pac[pt][1], bsc[1], bsh[1]), 0.f);
    float v2 = fmaxf(fmaf(pac[pt][2], bsc[2], bsh[2]), 0.f);
    float v3 = fmaxf(fmaf(pac[pt][3], bsc[3], bsh[3]), 0.f);
    ((unsigned*)s_rT)[pp * LDW + q * 8 + quad * 2 + 0] = packbf2(v0, v1);
    ((unsigned*)s_rT)[pp * LDW + q * 8 + quad * 2 + 1] = packbf2(v2, v3);
  }

  // ---------------- Phase 2: 2 barriers per group ----------------
  float* s_w = s_u;                          // [49 k][132] fp32
  const int cgA = q + 4 * s;                 // this lane's 2 cg planes
  const int cgB = cgA + 8;
  const float* plA = s_xh + cgA * XPS;
  const float* plB = s_xh + cgB * XPS;
  const long opix = (h0 + py) * Wn + (w0 + px0);

  bar_lgkm();  // s_rT visible to all; xT(s_u) reads drained before s_w writes

  // involution helpers: load iter i into a named reg set / fma a set.
  auto ldi = [&](int i, f32x4* wr, f32x4* xv) {
#pragma unroll
    for (int jx = 0; jx < Kn; ++jx)
      wr[jx] = *(const f32x4*)(s_w + (i * Kn + jx) * WLD + py * 16 + px0);
    const float* rA = plA + (py + i) * XROW + px0;
    const float* rB = plB + (py + i) * XROW + px0;
    xv[0] = *(const f32x4*)rA; xv[1] = *(const f32x4*)(rA + 4); xv[2] = *(const f32x4*)(rA + 8);
    xv[3] = *(const f32x4*)rB; xv[4] = *(const f32x4*)(rB + 4); xv[5] = *(const f32x4*)(rB + 8);
  };

  for (int g = 0; g < Gn; ++g) {
    // ---- P0: halo writes + kernel-gen (A-frag from regs) -> s_w ----
#pragma unroll
    for (int it = 0; it < 21; ++it)          // linear: LDS offset == idx
      s_xh[t + it * 256] = ph[it];

    bf16x8 afr2[2];
#pragma unroll
    for (int ks = 0; ks < 2; ++ks) {
      unsigned* ap = (unsigned*)&afr2[ks];
      f32x4 lo = pA2[ks * 2], hi = pA2[ks * 2 + 1];
      ap[0] = packbf2(lo[0], lo[1]); ap[1] = packbf2(lo[2], lo[3]);
      ap[2] = packbf2(hi[0], hi[1]); ap[3] = packbf2(hi[2], hi[3]);
    }

    f32x4 wac[8];
#pragma unroll
    for (int pt = 0; pt < 8; ++pt) wac[pt] = (f32x4){0.f, 0.f, 0.f, 0.f};
#pragma unroll
    for (int ks = 0; ks < 2; ++ks) {
#pragma unroll
      for (int pt = 0; pt < 8; ++pt) {
        bf16x8 bf = *(const bf16x8*)(s_rT + (pt * 16 + m16) * LD + ks * 32 + quad * 8);
        wac[pt] = __builtin_amdgcn_mfma_f32_16x16x32_bf16(afr2[ks], bf, wac[pt], 0, 0, 0);
      }
    }
    {
      int kb = q * 16 + quad * 4;
#pragma unroll
      for (int r = 0; r < 4; ++r) {
        if (kb + r < KKn) {
#pragma unroll
          for (int pt = 0; pt < 8; ++pt)
            s_w[(kb + r) * WLD + pt * 16 + m16] = wac[pt][r];
        }
      }
    }
    bar_lgkm();

    // ---- P1: prefetch g+1 (flies over barriers) + pipelined involution ----
    if (g + 1 < Gn) issue_g(g + 1);

    f32x4 a0 = (f32x4){0.f, 0.f, 0.f, 0.f};
    f32x4 a1 = (f32x4){0.f, 0.f, 0.f, 0.f};

    f32x4 wrA[7], xvA[6], wrB[7], xvB[6];
    auto fmai = [&](const f32x4* wr, const f32x4* xv) {
      float xa[12] = {xv[0][0], xv[0][1], xv[0][2], xv[0][3],
                      xv[1][0], xv[1][1], xv[1][2], xv[1][3],
                      xv[2][0], xv[2][1], xv[2][2], xv[2][3]};
      float xb[12] = {xv[3][0], xv[3][1], xv[3][2], xv[3][3],
                      xv[4][0], xv[4][1], xv[4][2], xv[4][3],
                      xv[5][0], xv[5][1], xv[5][2], xv[5][3]};
#pragma unroll
      for (int jx = 0; jx < Kn; ++jx) {
#pragma unroll
        for (int j = 0; j < 4; ++j) {
          a0[j] = fmaf(wr[jx][j], xa[jx + j], a0[j]);
          a1[j] = fmaf(wr[jx][j], xb[jx + j], a1[j]);
        }
      }
    };

    // depth-2 software pipeline: reads for iter i+1 issue before fma of i.
    ldi(0, wrA, xvA);
    ldi(1, wrB, xvB);
    fmai(wrA, xvA);          // i=0
    ldi(2, wrA, xvA);
    fmai(wrB, xvB);          // i=1
    ldi(3, wrB, xvB);
    fmai(wrA, xvA);          // i=2
    ldi(4, wrA, xvA);
    fmai(wrB, xvB);          // i=3
    ldi(5, wrB, xvB);
    fmai(wrA, xvA);          // i=4
    ldi(6, wrA, xvA);
    fmai(wrB, xvB);          // i=5
    fmai(wrA, xvA);          // i=6

    float* ob = out + xbase + (long)(g * CGn) * HWn + opix;
    *(f32x4*)(ob + (long)cgA * HWn) = a0;
    *(f32x4*)(ob + (long)cgB * HWn) = a1;

    bar_lgkm();  // invol reads of s_w/s_xh drained before next P0 overwrites
  }
}

extern "C" void kernel_launch(void* const* d_in, const int* in_sizes, int n_in,
                              void* d_out, int out_size, void* d_ws, size_t ws_size,
                              hipStream_t stream) {
  const float* x        = (const float*)d_in[0];
  const float* w_reduce = (const float*)d_in[1];
  const float* w_span   = (const float*)d_in[2];
  const float* bn_gamma = (const float*)d_in[3];
  const float* bn_beta  = (const float*)d_in[4];
  const float* bn_mean  = (const float*)d_in[5];
  const float* bn_var   = (const float*)d_in[6];
  float* outp = (float*)d_out;

  dim3 grid(512, 1, 1);  // 1-D for XCD-aware swizzle; 2 blocks/CU
  invol_fused<<<grid, 256, 0, stream>>>(x, w_reduce, w_span, bn_gamma,
                                        bn_beta, bn_mean, bn_var, outp);
}

// Round 10
// 170.404 us; speedup vs baseline: 2.2434x; 2.2434x over previous
//
#include <hip/hip_runtime.h>

// Involution2d fused, MFMA + sliding-window involution.
// Block = (batch, 8-row x 16-col tile), 256 threads / 4 waves.
// Phase 1: rT[p][o] = bf16(ReLU(BN(w_reduce @ x)))   via mfma 16x16x32 bf16
// Phase 2 per group: P0 {halo LDS writes + kernel-gen MFMA -> s_w} / bar /
//   P1 {prefetch g+1 + involution 4px x 2 planes per lane, all 4 waves} / bar.
// R2: lgkm-only barriers + register-staged prefetch (300->106us).
// R4 FAILED: wave-specialized staging -> scratch spills.
// R5 NEG: LDS volume cut with 2 feeding waves -> pipe starved, slower.
// R7: s_a eliminated, 2 barriers/group (106->101).
// R8: XCD swizzle, FETCH 230->67MB (92us). LDS-pipe ledger: ~93% busy ->
//     LDS throughput is THE wall.
// R9 FAILED: depth-2 pipeline passed f32x4 arrays BY POINTER through
//     lambdas -> SROA failed -> scratch (WRITE 353MB, 382us). Lesson:
//     local arrays only as literal-indexed unrolled in-place (pac/wac).
// R10: kill the redundant 16% of the LDS budget - s_rT kgen fragments are
//     group-invariant: cache once in rt[2][8] named-pattern regs after the
//     pre-loop barrier; kgen B-operand becomes pure-register. s_rT is then
//     dead -> alias s_xh into its LDS (union): 66 -> 47.4KB/block, opening
//     3 blocks/CU if VGPR allows (>=2 guaranteed by launch_bounds).

typedef __attribute__((ext_vector_type(8))) short bf16x8;
typedef __attribute__((ext_vector_type(4))) float f32x4;

namespace {
constexpr int Cn = 256, Hn = 64, Wn = 64, HWn = 4096;
constexpr int Gn = 16, CGn = 16, CRn = 64;
constexpr int Kn = 7, PADn = 3, KKn = 49;
constexpr int TH = 8, TW = 16, TP = 128;   // tile pixels
constexpr int LD = 72, LDW = 36;           // bf16 row stride (64 + 8 pad) / dwords
constexpr int WLD = 132;                   // s_w fp32 row stride (128 px + 4 pad)
constexpr int XROW = 24, XPS = 336;        // halo row / plane stride (dwords); linear
constexpr int SM_A  = KKn * WLD * 4;       // 25872 B: s_u (xT / s_w)
constexpr int SM_B  = 16 * XPS * 4;        // 21504 B: union(s_rT 18432, s_xh)
}

__device__ __forceinline__ unsigned short bf16rne(float f) {
  unsigned u = __float_as_uint(f);
  u += 0x7fffu + ((u >> 16) & 1u);
  return (unsigned short)(u >> 16);
}
__device__ __forceinline__ unsigned packbf2(float a, float b) {
  return (unsigned)bf16rne(a) | ((unsigned)bf16rne(b) << 16);
}

// lgkm-only barrier: LDS producer/consumer ordering WITHOUT draining vmcnt,
// so register-staged global prefetch loads stay in flight across it.
__device__ __forceinline__ void bar_lgkm() {
  asm volatile("s_waitcnt lgkmcnt(0)" ::: "memory");
  __builtin_amdgcn_s_barrier();
}

__global__ __launch_bounds__(256, 2) void invol_fused(
    const float* __restrict__ x, const float* __restrict__ w_reduce,
    const float* __restrict__ w_span, const float* __restrict__ bn_gamma,
    const float* __restrict__ bn_beta, const float* __restrict__ bn_mean,
    const float* __restrict__ bn_var, float* __restrict__ out)
{
  __shared__ __align__(16) char smem[SM_A + SM_B];         // 47.4 KB total
  float* s_u = (float*)smem;                               // ph1 xT / ph2 s_w
  unsigned short* s_rT = (unsigned short*)(smem + SM_A);   // ph1 result (dies at rt-cache)
  float* s_xh = (float*)(smem + SM_A);                     // ph2 halo (aliases s_rT)

  const int t = threadIdx.x;
  const int lane = t & 63, q = t >> 6;
  const int m16 = lane & 15, quad = lane >> 4;
  const int s = lane >> 5;                 // half of wave -> cg split
  const int slot = lane & 31;
  const int py = slot >> 2, px0 = (slot & 3) * 4;

  // XCD-aware block swizzle: batch b -> XCD b&7; a batch's 32 tiles share
  // one XCD's L2 so group x-slabs are fetched once per XCD (R8: -71% FETCH).
  const int bid = blockIdx.x;              // 0..511
  const int xcd = bid & 7;
  const int jj  = bid >> 3;                // 0..63 within XCD
  const int b   = xcd + 8 * (jj >> 5);     // batches {xcd, xcd+8}
  const int tile = jj & 31;                // 0..31 -> 8x4 tile grid
  const int h0 = (tile >> 2) * TH;
  const int w0 = (tile & 3) * TW;
  const long xbase = (long)b * Cn * HWn;

  // BN constants for this lane's phase-1 D rows (o = q*16 + quad*4 + r)
  float bsc[4], bsh[4];
  {
    int ob = q * 16 + quad * 4;
#pragma unroll
    for (int r = 0; r < 4; ++r) {
      float sc = bn_gamma[ob + r] * rsqrtf(bn_var[ob + r] + 1e-5f);
      bsc[r] = sc;
      bsh[r] = bn_beta[ob + r] - bn_mean[ob + r] * sc;
    }
  }

  // ---------------- Phase 1: rT = bf16(ReLU(BN(w_reduce @ x))) ----------------
  f32x4 pac[8];
#pragma unroll
  for (int pt = 0; pt < 8; ++pt) pac[pt] = (f32x4){0.f, 0.f, 0.f, 0.f};

  unsigned short* xT = (unsigned short*)s_u;  // [128 p][72] bf16

  float pxa[16], pxb[16];
  f32x4 pA1[4];
  const float* wrrow = w_reduce + (q * 16 + m16) * Cn;   // this lane's A row

  auto issue_cc = [&](int cc) {
#pragma unroll
    for (int h = 0; h < 4; ++h)   // A frag: cols cc + ks*32 + quad*8 + h4
      pA1[h] = *(const f32x4*)(wrrow + cc + (h >> 1) * 32 + quad * 8 + (h & 1) * 4);
#pragma unroll
    for (int it = 0; it < 16; ++it) {
      int idx = t + it * 256;
      int pp = idx & 127, cp = idx >> 7;
      const float* gp = x + xbase + (long)(cc + cp * 2) * HWn
                        + (h0 + (pp >> 4)) * Wn + (w0 + (pp & 15));
      pxa[it] = gp[0];
      pxb[it] = gp[HWn];
    }
  };

  issue_cc(0);
  for (int cc = 0; cc < Cn; cc += 64) {
    bar_lgkm();
#pragma unroll
    for (int it = 0; it < 16; ++it) {       // xT[p][c] bf16 (2 ch packed)
      int idx = t + it * 256;
      int pp = idx & 127, cp = idx >> 7;
      ((unsigned*)xT)[pp * LDW + cp] = packbf2(pxa[it], pxb[it]);
    }
    bf16x8 afr[2];                          // pack A-frag before regs reused
#pragma unroll
    for (int ks = 0; ks < 2; ++ks) {
      unsigned* ap = (unsigned*)&afr[ks];
      f32x4 lo = pA1[ks * 2], hi = pA1[ks * 2 + 1];
      ap[0] = packbf2(lo[0], lo[1]); ap[1] = packbf2(lo[2], lo[3]);
      ap[2] = packbf2(hi[0], hi[1]); ap[3] = packbf2(hi[2], hi[3]);
    }
    if (cc + 64 < Cn) issue_cc(cc + 64);    // prefetch next cc-step
    bar_lgkm();
#pragma unroll
    for (int ks = 0; ks < 2; ++ks) {
#pragma unroll
      for (int pt = 0; pt < 8; ++pt) {
        bf16x8 bf = *(const bf16x8*)(xT + (pt * 16 + m16) * LD + ks * 32 + quad * 8);
        pac[pt] = __builtin_amdgcn_mfma_f32_16x16x32_bf16(afr[ks], bf, pac[pt], 0, 0, 0);
      }
    }
  }

  // g-invariant halo addressing, hoisted: plane-relative offset or -1.
  int hoff[21];
#pragma unroll
  for (int it = 0; it < 21; ++it) {
    int idx = t + it * 256;
    int pl = idx / 336, rem = idx - pl * 336;
    int iy = rem / XROW, ix = rem - iy * XROW;   // ix 22,23: harmless pad
    int gy = h0 + iy - PADn, gx = w0 + ix - PADn;
    hoff[it] = ((unsigned)gy < (unsigned)Hn && (unsigned)gx < (unsigned)Wn)
                   ? pl * HWn + gy * Wn + gx : -1;
  }

  // phase-2 staging regs (all 256 threads; proven spill-free scale)
  float ph[21];
  f32x4 pA2[4];
  const int wrow = q * 16 + m16;            // A row for kgen (rows>=49 discarded)
  const int wclamp = (wrow < KKn ? wrow : 0);
  auto issue_g = [&](int g) {
    const float* wsrow = w_span + ((long)g * KKn + wclamp) * CRn;
#pragma unroll
    for (int h = 0; h < 4; ++h)
      pA2[h] = *(const f32x4*)(wsrow + (h >> 1) * 32 + quad * 8 + (h & 1) * 4);
    const float* xg = x + xbase + (long)g * CGn * HWn;
#pragma unroll
    for (int it = 0; it < 21; ++it)
      ph[it] = (hoff[it] >= 0) ? xg[hoff[it]] : 0.f;
  };

  issue_g(0);  // loads fly over epilogue + pre-loop barriers

  // epilogue: BN+ReLU -> rT[p][o] bf16 pairs
#pragma unroll
  for (int pt = 0; pt < 8; ++pt) {
    int pp = pt * 16 + m16;
    float v0 = fmaxf(fmaf(pac[pt][0], bsc[0], bsh[0]), 0.f);
    float v1 = fmaxf(fmaf(pac[pt][1], bsc[1], bsh[1]), 0.f);
    float v2 = fmaxf(fmaf(pac[pt][2], bsc[2], bsh[2]), 0.f);
    float v3 = fmaxf(fmaf(pac[pt][3], bsc[3], bsh[3]), 0.f);
    ((unsigned*)s_rT)[pp * LDW + q * 8 + quad * 2 + 0] = packbf2(v0, v1);
    ((unsigned*)s_rT)[pp * LDW + q * 8 + quad * 2 + 1] = packbf2(v2, v3);
  }

  bar_lgkm();  // s_rT visible to all; xT(s_u) reads drained

  // rt-cache: kgen B-fragments are group-invariant -> read ONCE into regs.
  // (literal-indexed unrolled array == proven pac/wac promotion pattern)
  bf16x8 rt[2][8];
#pragma unroll
  for (int ks = 0; ks < 2; ++ks)
#pragma unroll
    for (int pt = 0; pt < 8; ++pt)
      rt[ks][pt] = *(const bf16x8*)(s_rT + (pt * 16 + m16) * LD + ks * 32 + quad * 8);

  bar_lgkm();  // ALL waves' rt reads done before s_xh overwrites s_rT space

  // ---------------- Phase 2: 2 barriers per group ----------------
  float* s_w = s_u;                          // [49 k][132] fp32
  const int cgA = q + 4 * s;                 // this lane's 2 cg planes
  const int cgB = cgA + 8;
  const float* plA = s_xh + cgA * XPS;
  const float* plB = s_xh + cgB * XPS;
  const long opix = (h0 + py) * Wn + (w0 + px0);

  for (int g = 0; g < Gn; ++g) {
    // ---- P0: halo writes + kernel-gen (A and B frags from regs) -> s_w ----
#pragma unroll
    for (int it = 0; it < 21; ++it)          // linear: LDS offset == idx
      s_xh[t + it * 256] = ph[it];

    bf16x8 afr2[2];
#pragma unroll
    for (int ks = 0; ks < 2; ++ks) {
      unsigned* ap = (unsigned*)&afr2[ks];
      f32x4 lo = pA2[ks * 2], hi = pA2[ks * 2 + 1];
      ap[0] = packbf2(lo[0], lo[1]); ap[1] = packbf2(lo[2], lo[3]);
      ap[2] = packbf2(hi[0], hi[1]); ap[3] = packbf2(hi[2], hi[3]);
    }

    f32x4 wac[8];
#pragma unroll
    for (int pt = 0; pt < 8; ++pt) wac[pt] = (f32x4){0.f, 0.f, 0.f, 0.f};
#pragma unroll
    for (int ks = 0; ks < 2; ++ks) {
#pragma unroll
      for (int pt = 0; pt < 8; ++pt)
        wac[pt] = __builtin_amdgcn_mfma_f32_16x16x32_bf16(afr2[ks], rt[ks][pt], wac[pt], 0, 0, 0);
    }
    {
      int kb = q * 16 + quad * 4;
#pragma unroll
      for (int r = 0; r < 4; ++r) {
        if (kb + r < KKn) {
#pragma unroll
          for (int pt = 0; pt < 8; ++pt)
            s_w[(kb + r) * WLD + pt * 16 + m16] = wac[pt][r];
        }
      }
    }
    bar_lgkm();

    // ---- P1: prefetch g+1 (flies over barriers) + involution ----
    if (g + 1 < Gn) issue_g(g + 1);

    f32x4 a0 = (f32x4){0.f, 0.f, 0.f, 0.f};
    f32x4 a1 = (f32x4){0.f, 0.f, 0.f, 0.f};
#pragma unroll 1
    for (int i = 0; i < Kn; ++i) {
      f32x4 wr_[7];
#pragma unroll
      for (int jx = 0; jx < Kn; ++jx)
        wr_[jx] = *(const f32x4*)(s_w + (i * Kn + jx) * WLD + py * 16 + px0);
      const float* rA = plA + (py + i) * XROW + px0;
      const float* rB = plB + (py + i) * XROW + px0;
      f32x4 xa0 = *(const f32x4*)rA, xa1 = *(const f32x4*)(rA + 4), xa2 = *(const f32x4*)(rA + 8);
      f32x4 xb0 = *(const f32x4*)rB, xb1 = *(const f32x4*)(rB + 4), xb2 = *(const f32x4*)(rB + 8);
      float xa[12] = {xa0[0], xa0[1], xa0[2], xa0[3], xa1[0], xa1[1], xa1[2], xa1[3],
                      xa2[0], xa2[1], xa2[2], xa2[3]};
      float xb[12] = {xb0[0], xb0[1], xb0[2], xb0[3], xb1[0], xb1[1], xb1[2], xb1[3],
                      xb2[0], xb2[1], xb2[2], xb2[3]};
#pragma unroll
      for (int jx = 0; jx < Kn; ++jx) {
#pragma unroll
        for (int j = 0; j < 4; ++j) {
          a0[j] = fmaf(wr_[jx][j], xa[jx + j], a0[j]);
          a1[j] = fmaf(wr_[jx][j], xb[jx + j], a1[j]);
        }
      }
    }
    float* ob = out + xbase + (long)(g * CGn) * HWn + opix;
    *(f32x4*)(ob + (long)cgA * HWn) = a0;
    *(f32x4*)(ob + (long)cgB * HWn) = a1;

    bar_lgkm();  // invol reads of s_w/s_xh drained before next P0 overwrites
  }
}

extern "C" void kernel_launch(void* const* d_in, const int* in_sizes, int n_in,
                              void* d_out, int out_size, void* d_ws, size_t ws_size,
                              hipStream_t stream) {
  const float* x        = (const float*)d_in[0];
  const float* w_reduce = (const float*)d_in[1];
  const float* w_span   = (const float*)d_in[2];
  const float* bn_gamma = (const float*)d_in[3];
  const float* bn_beta  = (const float*)d_in[4];
  const float* bn_mean  = (const float*)d_in[5];
  const float* bn_var   = (const float*)d_in[6];
  float* outp = (float*)d_out;

  dim3 grid(512, 1, 1);  // 1-D for XCD-aware swizzle
  invol_fused<<<grid, 256, 0, stream>>>(x, w_reduce, w_span, bn_gamma,
                                        bn_beta, bn_mean, bn_var, outp);
}